// Round 4
// baseline (3222.152 us; speedup 1.0000x reference)
//
#include <hip/hip_runtime.h>

#define N_TOTAL 1024000
#define N_EDGES 16384000
#define SLOPE 0.01f
#define NBUCK 500        // coarse buckets of 2048 dst nodes (500*2048 == N_TOTAL)
#define NPB   2048
#define BCAP  36864      // per-bucket capacity; mean 32768, sigma ~181 -> +22 sigma
#define TILE  8192       // edges per binning tile

__device__ __forceinline__ float lrelu(float v){ return v > 0.0f ? v : SLOPE*v; }

// ---------------- node kernels ----------------

// P[i] = x[i] @ w0a   (bias added later by aggregator)
__global__ void __launch_bounds__(256) k_init(const float* __restrict__ x,
                       const float* __restrict__ w,   // 16x8
                       float* __restrict__ P){
  int i = blockIdx.x*256 + threadIdx.x;
  if (i >= N_TOTAL) return;
  const float4* xr = (const float4*)(x + (size_t)i*16);
  float4 a0 = xr[0], a1 = xr[1], a2 = xr[2], a3 = xr[3];
  float xi[16] = {a0.x,a0.y,a0.z,a0.w, a1.x,a1.y,a1.z,a1.w,
                  a2.x,a2.y,a2.z,a2.w, a3.x,a3.y,a3.z,a3.w};
  float p[8];
  #pragma unroll
  for (int j=0;j<8;j++){
    float s = 0.f;
    #pragma unroll
    for (int k=0;k<16;k++) s += xi[k]*w[k*8+j];
    p[j] = s;
  }
  float4* Pr = (float4*)(P + (size_t)i*8);
  Pr[0] = make_float4(p[0],p[1],p[2],p[3]);
  Pr[1] = make_float4(p[4],p[5],p[6],p[7]);
}

// Q -> lrelu -> @wb+bb -> lrelu -> @wa -> P
__global__ void __launch_bounds__(256) k_mid(float* __restrict__ P, const float* __restrict__ Q,
                      const float* __restrict__ wb, const float* __restrict__ bb,
                      const float* __restrict__ wa){
  int i = blockIdx.x*256 + threadIdx.x;
  if (i >= N_TOTAL) return;
  const float4* Qr = (const float4*)(Q + (size_t)i*8);
  float4 q0 = Qr[0], q1 = Qr[1];
  float g[8] = {lrelu(q0.x),lrelu(q0.y),lrelu(q0.z),lrelu(q0.w),
                lrelu(q1.x),lrelu(q1.y),lrelu(q1.z),lrelu(q1.w)};
  float h[8];
  #pragma unroll
  for (int j=0;j<8;j++){
    float s = bb[j];
    #pragma unroll
    for (int k=0;k<8;k++) s += g[k]*wb[k*8+j];
    h[j] = lrelu(s);
  }
  float p[8];
  #pragma unroll
  for (int j=0;j<8;j++){
    float s = 0.f;
    #pragma unroll
    for (int k=0;k<8;k++) s += h[k]*wa[k*8+j];
    p[j] = s;
  }
  float4* Pr = (float4*)(P + (size_t)i*8);
  Pr[0] = make_float4(p[0],p[1],p[2],p[3]);
  Pr[1] = make_float4(p[4],p[5],p[6],p[7]);
}

// ---------------- tile-sort binning (line-dense writes) ----------------
// Each block: 8192-edge tile -> LDS hist over 500 buckets -> scan ->
// 1 global atomic per (bucket,tile) -> compact in LDS -> contiguous copy-out.
__global__ void __launch_bounds__(256) k_bin2(const int* __restrict__ src, const int* __restrict__ dst,
                                              int* __restrict__ cnt, int* __restrict__ packed){
  __shared__ int tilebuf[TILE];
  __shared__ int hist[512], offs[512], cur[512], gbase[512];
  __shared__ int s2[256];
  int tid = threadIdx.x;
  int base = blockIdx.x * TILE;
  hist[tid] = 0; hist[tid+256] = 0;
  cur[tid]  = 0; cur[tid+256]  = 0;
  __syncthreads();
  #pragma unroll
  for (int k = 0; k < TILE/256; k++){
    int d = dst[base + k*256 + tid];
    atomicAdd(&hist[d >> 11], 1);
  }
  __syncthreads();
  int h0 = hist[2*tid], h1 = hist[2*tid+1];
  s2[tid] = h0 + h1;
  __syncthreads();
  for (int off = 1; off < 256; off <<= 1){
    int t = (tid >= off) ? s2[tid-off] : 0;
    __syncthreads();
    s2[tid] += t;
    __syncthreads();
  }
  int ex = s2[tid] - (h0 + h1);          // exclusive over pairs
  offs[2*tid]   = ex;
  offs[2*tid+1] = ex + h0;
  if (2*tid   < NBUCK) gbase[2*tid]   = atomicAdd(&cnt[2*tid],   h0);
  if (2*tid+1 < NBUCK) gbase[2*tid+1] = atomicAdd(&cnt[2*tid+1], h1);
  __syncthreads();
  #pragma unroll
  for (int k = 0; k < TILE/256; k++){
    int idx = base + k*256 + tid;
    int d = dst[idx], s = src[idx];
    int b = d >> 11, l = d & 2047;
    int p = offs[b] + atomicAdd(&cur[b], 1);
    tilebuf[p] = (l << 20) | s;          // 11b local | 20b src = 31 bits
  }
  __syncthreads();
  int wv = tid >> 6, ln = tid & 63;
  for (int b = wv; b < NBUCK; b += 4){
    int n = hist[b], g = gbase[b], o = offs[b];
    if (g >= BCAP) continue;
    if (g + n > BCAP) n = BCAP - g;
    int* dp = packed + (size_t)b * BCAP + g;
    for (int i = ln; i < n; i += 64) dp[i] = tilebuf[o + i];
  }
}

// ---------------- bucketed aggregation (LDS accumulate, no sort) ----------------
// One block per bucket. acc[j][l] transposed so ds_add bank = l&31 (random -> ~2-way).
__global__ void __launch_bounds__(256) k_aggb(const float* __restrict__ P,
                                              const int* __restrict__ cnt,
                                              const int* __restrict__ packed,
                                              const float* __restrict__ bias,
                                              float* __restrict__ Q){
  __shared__ float acc[8*NPB];           // 64 KB
  int b = blockIdx.x, tid = threadIdx.x;
  for (int k = tid; k < 8*NPB; k += 256) acc[k] = 0.f;
  __syncthreads();
  int n = cnt[b]; if (n > BCAP) n = BCAP;
  const int* region = packed + (size_t)b * BCAP;
  int i = tid;
  for (; i + 256 < n; i += 512){
    int e0 = region[i], e1 = region[i+256];
    int l0 = e0 >> 20, s0 = e0 & 0xFFFFF;
    int l1 = e1 >> 20, s1 = e1 & 0xFFFFF;
    const float4* p0 = (const float4*)(P + (size_t)s0*8);
    const float4* p1 = (const float4*)(P + (size_t)s1*8);
    float4 a0 = p0[0], a1 = p0[1];
    float4 c0 = p1[0], c1 = p1[1];
    atomicAdd(&acc[0*NPB+l0], a0.x); atomicAdd(&acc[1*NPB+l0], a0.y);
    atomicAdd(&acc[2*NPB+l0], a0.z); atomicAdd(&acc[3*NPB+l0], a0.w);
    atomicAdd(&acc[4*NPB+l0], a1.x); atomicAdd(&acc[5*NPB+l0], a1.y);
    atomicAdd(&acc[6*NPB+l0], a1.z); atomicAdd(&acc[7*NPB+l0], a1.w);
    atomicAdd(&acc[0*NPB+l1], c0.x); atomicAdd(&acc[1*NPB+l1], c0.y);
    atomicAdd(&acc[2*NPB+l1], c0.z); atomicAdd(&acc[3*NPB+l1], c0.w);
    atomicAdd(&acc[4*NPB+l1], c1.x); atomicAdd(&acc[5*NPB+l1], c1.y);
    atomicAdd(&acc[6*NPB+l1], c1.z); atomicAdd(&acc[7*NPB+l1], c1.w);
  }
  for (; i < n; i += 256){
    int e0 = region[i];
    int l0 = e0 >> 20, s0 = e0 & 0xFFFFF;
    const float4* p0 = (const float4*)(P + (size_t)s0*8);
    float4 a0 = p0[0], a1 = p0[1];
    atomicAdd(&acc[0*NPB+l0], a0.x); atomicAdd(&acc[1*NPB+l0], a0.y);
    atomicAdd(&acc[2*NPB+l0], a0.z); atomicAdd(&acc[3*NPB+l0], a0.w);
    atomicAdd(&acc[4*NPB+l0], a1.x); atomicAdd(&acc[5*NPB+l0], a1.y);
    atomicAdd(&acc[6*NPB+l0], a1.z); atomicAdd(&acc[7*NPB+l0], a1.w);
  }
  __syncthreads();
  float b0 = bias[0], b1 = bias[1], b2 = bias[2], b3 = bias[3];
  float b4 = bias[4], b5 = bias[5], b6 = bias[6], b7 = bias[7];
  int nodebase = b * NPB;
  #pragma unroll
  for (int k = 0; k < NPB/256; k++){
    int l = k*256 + tid;                 // LDS reads conflict-free (consecutive l)
    int node = nodebase + l;
    const float4* pr = (const float4*)(P + (size_t)node*8);
    float4 sp0 = pr[0], sp1 = pr[1];
    float4 q0 = make_float4(acc[0*NPB+l]+sp0.x+b0, acc[1*NPB+l]+sp0.y+b1,
                            acc[2*NPB+l]+sp0.z+b2, acc[3*NPB+l]+sp0.w+b3);
    float4 q1 = make_float4(acc[4*NPB+l]+sp1.x+b4, acc[5*NPB+l]+sp1.y+b5,
                            acc[6*NPB+l]+sp1.z+b6, acc[7*NPB+l]+sp1.w+b7);
    float4* qr = (float4*)(Q + (size_t)node*8);
    qr[0] = q0; qr[1] = q1;
  }
}

// ---------------- fallback (atomic path) ----------------
__global__ void __launch_bounds__(256) k_qinit(const float* __restrict__ P, const float* __restrict__ b,
                                               float* __restrict__ Q){
  int t = blockIdx.x*256 + threadIdx.x;
  if (t < N_TOTAL*8) Q[t] = P[t] + b[t & 7];
}

__global__ void __launch_bounds__(256) k_scatter(const int* __restrict__ src,
                                                 const int* __restrict__ dst,
                                                 const float* __restrict__ P,
                                                 float* __restrict__ Q){
  int t = blockIdx.x*256 + threadIdx.x;
  int e = t >> 3;
  int j = t & 7;
  int s = src[e];
  int d = dst[e];
  float v = P[(size_t)s*8 + j];
  atomicAdd(Q + (size_t)d*8 + j, v);
}

// ---------------- readout ----------------
__global__ void __launch_bounds__(256) k_readout(const float* __restrict__ Q,
                          const float* __restrict__ wb, const float* __restrict__ bb,
                          const float* __restrict__ fc1w, const float* __restrict__ fc1b,
                          const float* __restrict__ fc2w, const float* __restrict__ fc2b,
                          float* __restrict__ out){
  int bi = blockIdx.x;
  int tid = threadIdx.x;
  float acc0 = 0.f, acc1 = 0.f;
  for (int n = tid; n < 2000; n += 256){
    size_t i = (size_t)bi*2000 + n;
    const float4* qr = (const float4*)(Q + i*8);
    float4 q0 = qr[0], q1 = qr[1];
    float g[8] = {lrelu(q0.x),lrelu(q0.y),lrelu(q0.z),lrelu(q0.w),
                  lrelu(q1.x),lrelu(q1.y),lrelu(q1.z),lrelu(q1.w)};
    float s = fc1b[0];
    #pragma unroll
    for (int j=0;j<8;j++){
      float h = bb[j];
      #pragma unroll
      for (int k=0;k<8;k++) h += g[k]*wb[k*8+j];
      s += lrelu(h)*fc1w[j];
    }
    float t = lrelu(s);
    acc0 += t*fc2w[n*2+0];
    acc1 += t*fc2w[n*2+1];
  }
  #pragma unroll
  for (int off = 32; off > 0; off >>= 1){
    acc0 += __shfl_down(acc0, off);
    acc1 += __shfl_down(acc1, off);
  }
  __shared__ float s0[4], s1[4];
  int w = tid >> 6;
  if ((tid & 63) == 0){ s0[w] = acc0; s1[w] = acc1; }
  __syncthreads();
  if (tid == 0){
    float z0 = s0[0]+s0[1]+s0[2]+s0[3] + fc2b[0];
    float z1 = s1[0]+s1[1]+s1[2]+s1[3] + fc2b[1];
    float m = fmaxf(z0, z1);
    float lse = m + logf(expf(z0-m) + expf(z1-m));
    out[bi*2+0] = z0 - lse;
    out[bi*2+1] = z1 - lse;
  }
}

extern "C" void kernel_launch(void* const* d_in, const int* in_sizes, int n_in,
                              void* d_out, int out_size, void* d_ws, size_t ws_size,
                              hipStream_t stream){
  const float* x   = (const float*)d_in[0];
  const int*   ei  = (const int*)d_in[1];
  const int*   src = ei;
  const int*   dst = ei + N_EDGES;
  const float* w0a=(const float*)d_in[3],  *b0a=(const float*)d_in[4];
  const float* w0b=(const float*)d_in[5],  *b0b=(const float*)d_in[6];
  const float* w1a=(const float*)d_in[7],  *b1a=(const float*)d_in[8];
  const float* w1b=(const float*)d_in[9],  *b1b=(const float*)d_in[10];
  const float* w2a=(const float*)d_in[11], *b2a=(const float*)d_in[12];
  const float* w2b=(const float*)d_in[13], *b2b=(const float*)d_in[14];
  const float* w3a=(const float*)d_in[15], *b3a=(const float*)d_in[16];
  const float* w3b=(const float*)d_in[17], *b3b=(const float*)d_in[18];
  const float* fc1w=(const float*)d_in[19],*fc1b=(const float*)d_in[20];
  const float* fc2w=(const float*)d_in[21],*fc2b=(const float*)d_in[22];
  float* out = (float*)d_out;

  // workspace layout
  char* base = (char*)d_ws;
  float* P      = (float*)base;  base += (size_t)N_TOTAL*8*4;      // 32.77 MB
  float* Q      = (float*)base;  base += (size_t)N_TOTAL*8*4;      // 32.77 MB
  size_t atomic_need = (size_t)(base - (char*)d_ws);
  int*   cnt    = (int*)base;    base += 512*4;                    // 2 KB
  int*   packed = (int*)base;    base += (size_t)NBUCK*BCAP*4;     // 73.73 MB
  size_t need = (size_t)(base - (char*)d_ws);

  const int nb_nodes = (N_TOTAL + 255)/256;   // 4000
  const int nb_tiles = N_EDGES / TILE;        // 2000
  const int nb_nf    = (N_TOTAL*8 + 255)/256; // 32000

  if (ws_size >= need){
    hipMemsetAsync(cnt, 0, 512*4, stream);
    k_bin2<<<nb_tiles,256,0,stream>>>(src, dst, cnt, packed);

    k_init<<<nb_nodes,256,0,stream>>>(x, w0a, P);
    k_aggb<<<NBUCK,256,0,stream>>>(P, cnt, packed, b0a, Q);
    k_mid <<<nb_nodes,256,0,stream>>>(P, Q, w0b, b0b, w1a);
    k_aggb<<<NBUCK,256,0,stream>>>(P, cnt, packed, b1a, Q);
    k_mid <<<nb_nodes,256,0,stream>>>(P, Q, w1b, b1b, w2a);
    k_aggb<<<NBUCK,256,0,stream>>>(P, cnt, packed, b2a, Q);
    k_mid <<<nb_nodes,256,0,stream>>>(P, Q, w2b, b2b, w3a);
    k_aggb<<<NBUCK,256,0,stream>>>(P, cnt, packed, b3a, Q);
  } else if (ws_size >= atomic_need){
    k_init<<<nb_nodes,256,0,stream>>>(x, w0a, P);
    k_qinit<<<nb_nf,256,0,stream>>>(P, b0a, Q);
    k_scatter<<<(N_EDGES*8)/256,256,0,stream>>>(src,dst,P,Q);
    k_mid <<<nb_nodes,256,0,stream>>>(P, Q, w0b, b0b, w1a);
    k_qinit<<<nb_nf,256,0,stream>>>(P, b1a, Q);
    k_scatter<<<(N_EDGES*8)/256,256,0,stream>>>(src,dst,P,Q);
    k_mid <<<nb_nodes,256,0,stream>>>(P, Q, w1b, b1b, w2a);
    k_qinit<<<nb_nf,256,0,stream>>>(P, b2a, Q);
    k_scatter<<<(N_EDGES*8)/256,256,0,stream>>>(src,dst,P,Q);
    k_mid <<<nb_nodes,256,0,stream>>>(P, Q, w2b, b2b, w3a);
    k_qinit<<<nb_nf,256,0,stream>>>(P, b3a, Q);
    k_scatter<<<(N_EDGES*8)/256,256,0,stream>>>(src,dst,P,Q);
  }
  k_readout<<<512,256,0,stream>>>(Q,w3b,b3b,fc1w,fc1b,fc2w,fc2b,out);
}

// Round 5
// 3188.077 us; speedup vs baseline: 1.0107x; 1.0107x over previous
//
#include <hip/hip_runtime.h>

#define N_TOTAL 1024000
#define N_EDGES 16384000
#define SLOPE 0.01f
#define NBUCK 500        // coarse buckets of 2048 dst nodes (500*2048 == N_TOTAL)
#define NPB   2048
#define BCAP  36864      // per-bucket capacity; mean 32768, sigma ~181 -> +22 sigma
#define TILE  8192       // edges per binning tile

__device__ __forceinline__ float lrelu(float v){ return v > 0.0f ? v : SLOPE*v; }

// ---------------- node kernels ----------------

// P[i] = x[i] @ w0a   (bias added later by aggregator)
__global__ void __launch_bounds__(256) k_init(const float* __restrict__ x,
                       const float* __restrict__ w,   // 16x8
                       float* __restrict__ P){
  int i = blockIdx.x*256 + threadIdx.x;
  if (i >= N_TOTAL) return;
  const float4* xr = (const float4*)(x + (size_t)i*16);
  float4 a0 = xr[0], a1 = xr[1], a2 = xr[2], a3 = xr[3];
  float xi[16] = {a0.x,a0.y,a0.z,a0.w, a1.x,a1.y,a1.z,a1.w,
                  a2.x,a2.y,a2.z,a2.w, a3.x,a3.y,a3.z,a3.w};
  float p[8];
  #pragma unroll
  for (int j=0;j<8;j++){
    float s = 0.f;
    #pragma unroll
    for (int k=0;k<16;k++) s += xi[k]*w[k*8+j];
    p[j] = s;
  }
  float4* Pr = (float4*)(P + (size_t)i*8);
  Pr[0] = make_float4(p[0],p[1],p[2],p[3]);
  Pr[1] = make_float4(p[4],p[5],p[6],p[7]);
}

// (fallback only) Q -> lrelu -> @wb+bb -> lrelu -> @wa -> P
__global__ void __launch_bounds__(256) k_mid(float* __restrict__ P, const float* __restrict__ Q,
                      const float* __restrict__ wb, const float* __restrict__ bb,
                      const float* __restrict__ wa){
  int i = blockIdx.x*256 + threadIdx.x;
  if (i >= N_TOTAL) return;
  const float4* Qr = (const float4*)(Q + (size_t)i*8);
  float4 q0 = Qr[0], q1 = Qr[1];
  float g[8] = {lrelu(q0.x),lrelu(q0.y),lrelu(q0.z),lrelu(q0.w),
                lrelu(q1.x),lrelu(q1.y),lrelu(q1.z),lrelu(q1.w)};
  float h[8];
  #pragma unroll
  for (int j=0;j<8;j++){
    float s = bb[j];
    #pragma unroll
    for (int k=0;k<8;k++) s += g[k]*wb[k*8+j];
    h[j] = lrelu(s);
  }
  float p[8];
  #pragma unroll
  for (int j=0;j<8;j++){
    float s = 0.f;
    #pragma unroll
    for (int k=0;k<8;k++) s += h[k]*wa[k*8+j];
    p[j] = s;
  }
  float4* Pr = (float4*)(P + (size_t)i*8);
  Pr[0] = make_float4(p[0],p[1],p[2],p[3]);
  Pr[1] = make_float4(p[4],p[5],p[6],p[7]);
}

// ---------------- tile-sort binning (line-dense writes) ----------------
__global__ void __launch_bounds__(256) k_bin2(const int* __restrict__ src, const int* __restrict__ dst,
                                              int* __restrict__ cnt, int* __restrict__ packed){
  __shared__ int tilebuf[TILE];
  __shared__ int hist[512], offs[512], cur[512], gbase[512];
  __shared__ int s2[256];
  int tid = threadIdx.x;
  int base = blockIdx.x * TILE;
  hist[tid] = 0; hist[tid+256] = 0;
  cur[tid]  = 0; cur[tid+256]  = 0;
  __syncthreads();
  #pragma unroll
  for (int k = 0; k < TILE/256; k++){
    int d = dst[base + k*256 + tid];
    atomicAdd(&hist[d >> 11], 1);
  }
  __syncthreads();
  int h0 = hist[2*tid], h1 = hist[2*tid+1];
  s2[tid] = h0 + h1;
  __syncthreads();
  for (int off = 1; off < 256; off <<= 1){
    int t = (tid >= off) ? s2[tid-off] : 0;
    __syncthreads();
    s2[tid] += t;
    __syncthreads();
  }
  int ex = s2[tid] - (h0 + h1);          // exclusive over pairs
  offs[2*tid]   = ex;
  offs[2*tid+1] = ex + h0;
  if (2*tid   < NBUCK) gbase[2*tid]   = atomicAdd(&cnt[2*tid],   h0);
  if (2*tid+1 < NBUCK) gbase[2*tid+1] = atomicAdd(&cnt[2*tid+1], h1);
  __syncthreads();
  #pragma unroll
  for (int k = 0; k < TILE/256; k++){
    int idx = base + k*256 + tid;
    int d = dst[idx], s = src[idx];
    int b = d >> 11, l = d & 2047;
    int p = offs[b] + atomicAdd(&cur[b], 1);
    tilebuf[p] = (l << 20) | s;          // 11b local | 20b src = 31 bits
  }
  __syncthreads();
  int wv = tid >> 6, ln = tid & 63;
  for (int b = wv; b < NBUCK; b += 4){
    int n = hist[b], g = gbase[b], o = offs[b];
    if (g >= BCAP) continue;
    if (g + n > BCAP) n = BCAP - g;
    int* dp = packed + (size_t)b * BCAP + g;
    for (int i = ln; i < n; i += 64) dp[i] = tilebuf[o + i];
  }
}

// ---------------- fused bucketed aggregation + MLP epilogue ----------------
// One block per bucket, 512 threads. acc[j][l] transposed: ds_add bank = l&31.
// fuse=1: Pout[i] = (lrelu(lrelu(q)@wb+bb))@wa ; fuse=0: Pout[i] = q (raw agg+bias)
__global__ void __launch_bounds__(512, 4) k_aggf(const float* __restrict__ Pin,
                                                 const int* __restrict__ cnt,
                                                 const int* __restrict__ packed,
                                                 const float* __restrict__ bias,
                                                 const float* __restrict__ wb,
                                                 const float* __restrict__ bb,
                                                 const float* __restrict__ wa,
                                                 int fuse,
                                                 float* __restrict__ Pout){
  __shared__ float acc[8*NPB];           // 64 KB
  int b = blockIdx.x, tid = threadIdx.x;
  for (int k = tid; k < 8*NPB; k += 512) acc[k] = 0.f;
  __syncthreads();
  int n = cnt[b]; if (n > BCAP) n = BCAP;
  const int* region = packed + (size_t)b * BCAP;
  int i = tid;
  for (; i + 512 < n; i += 1024){
    int e0 = region[i], e1 = region[i+512];
    int l0 = e0 >> 20, s0 = e0 & 0xFFFFF;
    int l1 = e1 >> 20, s1 = e1 & 0xFFFFF;
    const float4* p0 = (const float4*)(Pin + (size_t)s0*8);
    const float4* p1 = (const float4*)(Pin + (size_t)s1*8);
    float4 a0 = p0[0], a1 = p0[1];
    float4 c0 = p1[0], c1 = p1[1];
    atomicAdd(&acc[0*NPB+l0], a0.x); atomicAdd(&acc[1*NPB+l0], a0.y);
    atomicAdd(&acc[2*NPB+l0], a0.z); atomicAdd(&acc[3*NPB+l0], a0.w);
    atomicAdd(&acc[4*NPB+l0], a1.x); atomicAdd(&acc[5*NPB+l0], a1.y);
    atomicAdd(&acc[6*NPB+l0], a1.z); atomicAdd(&acc[7*NPB+l0], a1.w);
    atomicAdd(&acc[0*NPB+l1], c0.x); atomicAdd(&acc[1*NPB+l1], c0.y);
    atomicAdd(&acc[2*NPB+l1], c0.z); atomicAdd(&acc[3*NPB+l1], c0.w);
    atomicAdd(&acc[4*NPB+l1], c1.x); atomicAdd(&acc[5*NPB+l1], c1.y);
    atomicAdd(&acc[6*NPB+l1], c1.z); atomicAdd(&acc[7*NPB+l1], c1.w);
  }
  if (i < n){
    int e0 = region[i];
    int l0 = e0 >> 20, s0 = e0 & 0xFFFFF;
    const float4* p0 = (const float4*)(Pin + (size_t)s0*8);
    float4 a0 = p0[0], a1 = p0[1];
    atomicAdd(&acc[0*NPB+l0], a0.x); atomicAdd(&acc[1*NPB+l0], a0.y);
    atomicAdd(&acc[2*NPB+l0], a0.z); atomicAdd(&acc[3*NPB+l0], a0.w);
    atomicAdd(&acc[4*NPB+l0], a1.x); atomicAdd(&acc[5*NPB+l0], a1.y);
    atomicAdd(&acc[6*NPB+l0], a1.z); atomicAdd(&acc[7*NPB+l0], a1.w);
  }
  __syncthreads();
  float bv[8];
  #pragma unroll
  for (int j=0;j<8;j++) bv[j] = bias[j];
  int nodebase = b * NPB;
  #pragma unroll
  for (int k = 0; k < NPB/512; k++){
    int l = k*512 + tid;                 // LDS reads conflict-free
    int node = nodebase + l;
    const float4* pr = (const float4*)(Pin + (size_t)node*8);
    float4 sp0 = pr[0], sp1 = pr[1];
    float q[8] = {acc[0*NPB+l]+sp0.x+bv[0], acc[1*NPB+l]+sp0.y+bv[1],
                  acc[2*NPB+l]+sp0.z+bv[2], acc[3*NPB+l]+sp0.w+bv[3],
                  acc[4*NPB+l]+sp1.x+bv[4], acc[5*NPB+l]+sp1.y+bv[5],
                  acc[6*NPB+l]+sp1.z+bv[6], acc[7*NPB+l]+sp1.w+bv[7]};
    float4* qr = (float4*)(Pout + (size_t)node*8);
    if (fuse){
      float g[8];
      #pragma unroll
      for (int j=0;j<8;j++) g[j] = lrelu(q[j]);
      float h[8];
      #pragma unroll
      for (int j=0;j<8;j++){
        float s = bb[j];
        #pragma unroll
        for (int kk=0;kk<8;kk++) s += g[kk]*wb[kk*8+j];
        h[j] = lrelu(s);
      }
      float p[8];
      #pragma unroll
      for (int j=0;j<8;j++){
        float s = 0.f;
        #pragma unroll
        for (int kk=0;kk<8;kk++) s += h[kk]*wa[kk*8+j];
        p[j] = s;
      }
      qr[0] = make_float4(p[0],p[1],p[2],p[3]);
      qr[1] = make_float4(p[4],p[5],p[6],p[7]);
    } else {
      qr[0] = make_float4(q[0],q[1],q[2],q[3]);
      qr[1] = make_float4(q[4],q[5],q[6],q[7]);
    }
  }
}

// ---------------- fallback (atomic path) ----------------
__global__ void __launch_bounds__(256) k_qinit(const float* __restrict__ P, const float* __restrict__ b,
                                               float* __restrict__ Q){
  int t = blockIdx.x*256 + threadIdx.x;
  if (t < N_TOTAL*8) Q[t] = P[t] + b[t & 7];
}

__global__ void __launch_bounds__(256) k_scatter(const int* __restrict__ src,
                                                 const int* __restrict__ dst,
                                                 const float* __restrict__ P,
                                                 float* __restrict__ Q){
  int t = blockIdx.x*256 + threadIdx.x;
  int e = t >> 3;
  int j = t & 7;
  int s = src[e];
  int d = dst[e];
  float v = P[(size_t)s*8 + j];
  atomicAdd(Q + (size_t)d*8 + j, v);
}

// ---------------- readout ----------------
__global__ void __launch_bounds__(256) k_readout(const float* __restrict__ Q,
                          const float* __restrict__ wb, const float* __restrict__ bb,
                          const float* __restrict__ fc1w, const float* __restrict__ fc1b,
                          const float* __restrict__ fc2w, const float* __restrict__ fc2b,
                          float* __restrict__ out){
  int bi = blockIdx.x;
  int tid = threadIdx.x;
  float acc0 = 0.f, acc1 = 0.f;
  for (int n = tid; n < 2000; n += 256){
    size_t i = (size_t)bi*2000 + n;
    const float4* qr = (const float4*)(Q + i*8);
    float4 q0 = qr[0], q1 = qr[1];
    float g[8] = {lrelu(q0.x),lrelu(q0.y),lrelu(q0.z),lrelu(q0.w),
                  lrelu(q1.x),lrelu(q1.y),lrelu(q1.z),lrelu(q1.w)};
    float s = fc1b[0];
    #pragma unroll
    for (int j=0;j<8;j++){
      float h = bb[j];
      #pragma unroll
      for (int k=0;k<8;k++) h += g[k]*wb[k*8+j];
      s += lrelu(h)*fc1w[j];
    }
    float t = lrelu(s);
    acc0 += t*fc2w[n*2+0];
    acc1 += t*fc2w[n*2+1];
  }
  #pragma unroll
  for (int off = 32; off > 0; off >>= 1){
    acc0 += __shfl_down(acc0, off);
    acc1 += __shfl_down(acc1, off);
  }
  __shared__ float s0[4], s1[4];
  int w = tid >> 6;
  if ((tid & 63) == 0){ s0[w] = acc0; s1[w] = acc1; }
  __syncthreads();
  if (tid == 0){
    float z0 = s0[0]+s0[1]+s0[2]+s0[3] + fc2b[0];
    float z1 = s1[0]+s1[1]+s1[2]+s1[3] + fc2b[1];
    float m = fmaxf(z0, z1);
    float lse = m + logf(expf(z0-m) + expf(z1-m));
    out[bi*2+0] = z0 - lse;
    out[bi*2+1] = z1 - lse;
  }
}

extern "C" void kernel_launch(void* const* d_in, const int* in_sizes, int n_in,
                              void* d_out, int out_size, void* d_ws, size_t ws_size,
                              hipStream_t stream){
  const float* x   = (const float*)d_in[0];
  const int*   ei  = (const int*)d_in[1];
  const int*   src = ei;
  const int*   dst = ei + N_EDGES;
  const float* w0a=(const float*)d_in[3],  *b0a=(const float*)d_in[4];
  const float* w0b=(const float*)d_in[5],  *b0b=(const float*)d_in[6];
  const float* w1a=(const float*)d_in[7],  *b1a=(const float*)d_in[8];
  const float* w1b=(const float*)d_in[9],  *b1b=(const float*)d_in[10];
  const float* w2a=(const float*)d_in[11], *b2a=(const float*)d_in[12];
  const float* w2b=(const float*)d_in[13], *b2b=(const float*)d_in[14];
  const float* w3a=(const float*)d_in[15], *b3a=(const float*)d_in[16];
  const float* w3b=(const float*)d_in[17], *b3b=(const float*)d_in[18];
  const float* fc1w=(const float*)d_in[19],*fc1b=(const float*)d_in[20];
  const float* fc2w=(const float*)d_in[21],*fc2b=(const float*)d_in[22];
  float* out = (float*)d_out;

  // workspace layout: two ping-pong node buffers + packed edges
  char* base = (char*)d_ws;
  float* PA     = (float*)base;  base += (size_t)N_TOTAL*8*4;      // 32.77 MB
  float* PB     = (float*)base;  base += (size_t)N_TOTAL*8*4;      // 32.77 MB
  size_t atomic_need = (size_t)(base - (char*)d_ws);
  int*   cnt    = (int*)base;    base += 512*4;                    // 2 KB
  int*   packed = (int*)base;    base += (size_t)NBUCK*BCAP*4;     // 73.73 MB
  size_t need = (size_t)(base - (char*)d_ws);

  const int nb_nodes = (N_TOTAL + 255)/256;   // 4000
  const int nb_tiles = N_EDGES / TILE;        // 2000
  const int nb_nf    = (N_TOTAL*8 + 255)/256; // 32000

  if (ws_size >= need){
    hipMemsetAsync(cnt, 0, 512*4, stream);
    k_bin2<<<nb_tiles,256,0,stream>>>(src, dst, cnt, packed);

    k_init<<<nb_nodes,256,0,stream>>>(x, w0a, PA);
    // layer 0: agg(PA)+b0a -> MLP(w0b,b0b) -> lrelu -> @w1a -> PB
    k_aggf<<<NBUCK,512,0,stream>>>(PA, cnt, packed, b0a, w0b, b0b, w1a, 1, PB);
    // layer 1
    k_aggf<<<NBUCK,512,0,stream>>>(PB, cnt, packed, b1a, w1b, b1b, w2a, 1, PA);
    // layer 2
    k_aggf<<<NBUCK,512,0,stream>>>(PA, cnt, packed, b2a, w2b, b2b, w3a, 1, PB);
    // layer 3: raw agg+b3a -> PA (readout applies w3b/b3b)
    k_aggf<<<NBUCK,512,0,stream>>>(PB, cnt, packed, b3a, w0b, b0b, w0a, 0, PA);
    k_readout<<<512,256,0,stream>>>(PA,w3b,b3b,fc1w,fc1b,fc2w,fc2b,out);
  } else if (ws_size >= atomic_need){
    float* P = PA; float* Q = PB;
    k_init<<<nb_nodes,256,0,stream>>>(x, w0a, P);
    k_qinit<<<nb_nf,256,0,stream>>>(P, b0a, Q);
    k_scatter<<<(N_EDGES*8)/256,256,0,stream>>>(src,dst,P,Q);
    k_mid <<<nb_nodes,256,0,stream>>>(P, Q, w0b, b0b, w1a);
    k_qinit<<<nb_nf,256,0,stream>>>(P, b1a, Q);
    k_scatter<<<(N_EDGES*8)/256,256,0,stream>>>(src,dst,P,Q);
    k_mid <<<nb_nodes,256,0,stream>>>(P, Q, w1b, b1b, w2a);
    k_qinit<<<nb_nf,256,0,stream>>>(P, b2a, Q);
    k_scatter<<<(N_EDGES*8)/256,256,0,stream>>>(src,dst,P,Q);
    k_mid <<<nb_nodes,256,0,stream>>>(P, Q, w2b, b2b, w3a);
    k_qinit<<<nb_nf,256,0,stream>>>(P, b3a, Q);
    k_scatter<<<(N_EDGES*8)/256,256,0,stream>>>(src,dst,P,Q);
    k_readout<<<512,256,0,stream>>>(Q,w3b,b3b,fc1w,fc1b,fc2w,fc2b,out);
  }
}